// Round 14
// baseline (194.578 us; speedup 1.0000x reference)
//
#include <hip/hip_runtime.h>
#include <climits>

#define HW 262144          // 512*512
#define IW 512
#define RN 725             // virtual rotated canvas side
#define NSEG 256
#define CH_OFF 1536
#define TH_OFF 116736
#define XY_OFF 485376
#define NBLK 1024          // blocks per image plane in k_grad; minmax partial count
#define THP 16             // pixel splits in k_thist

static __device__ __forceinline__ float loadpix(const float* p, int y, int x, int n) {
    return (y >= 0 && y < n && x >= 0 && x < n) ? p[y * n + x] : 0.0f;
}

// virtual rot-canvas sample: canvas coord (cx,cy) -> nearest img pixel (exact rot formula)
static __device__ __forceinline__ float rtap(const float* __restrict__ im, int cx, int cy) {
    if (cx < 0 || cx >= RN || cy < 0 || cy >= RN) return 0.f;
    const float cs = 0.7071067811865476f;
    float xg = (float)cx - 362.0f;
    float yg = (float)cy - 362.0f;
    float xi = cs * xg - cs * yg + 255.5f;
    float yi = cs * xg + cs * yg + 255.5f;
    int xn = (int)rintf(xi);
    int yn = (int)rintf(yi);
    if (xn < 0 || xn >= IW || yn < 0 || yn >= IW) return 0.f;
    return im[yn * IW + xn];
}

// block-level min/max of map m's NBLK partials; all threads get (mn,mx)
static __device__ __forceinline__ void mm_of_map(const float* __restrict__ pmin,
                                                 const float* __restrict__ pmax,
                                                 int m, float* slo, float* shi,
                                                 float& mn, float& mx) {
    int tid = threadIdx.x;
    float lo = 3.4e38f, hi = -3.4e38f;
    for (int i = tid; i < NBLK; i += 256) {
        lo = fminf(lo, pmin[m * NBLK + i]);
        hi = fmaxf(hi, pmax[m * NBLK + i]);
    }
    slo[tid] = lo; shi[tid] = hi;
    __syncthreads();
    for (int off = 128; off > 0; off >>= 1) {
        if (tid < off) {
            slo[tid] = fminf(slo[tid], slo[tid + off]);
            shi[tid] = fmaxf(shi[tid], shi[tid + off]);
        }
        __syncthreads();
    }
    mn = slo[0]; mx = shi[0];
    __syncthreads();
}

// ---- gradients (f32) + LDS-tree min/max partials + init chores ----
// LDS tree (not __shfl_xor butterfly: 48 ds_swizzles/thread cost ~11us, r10).
// No cross-block handoff (threadfence last-block cost ~150us, r11); stream-ordered
// kernel boundaries are the cheapest device-wide barrier on MI355X.
__global__ __launch_bounds__(256) void k_grad(
    const float* __restrict__ img, float* __restrict__ gmaps,
    float* __restrict__ pmin, float* __restrict__ pmax,
    float* __restrict__ out, int* __restrict__ bbmin, int* __restrict__ bbmax)
{
    int bxx = blockIdx.x;
    int bc = blockIdx.y;
    int tid = threadIdx.x;
    // init chores for later-launched consumers (stream order covers visibility)
    if (bc == 0 && bxx < 456) {                 // zero rs+ch: 456*256 == TH_OFF
        out[bxx * 256 + tid] = 0.0f;
    } else if (bc == 1 && bxx < 12) {           // bbox init: 12*256 == 2*3072
        int i = bxx * 256 + tid;
        bbmin[i] = INT_MAX;
        bbmax[i] = INT_MIN;
    }
    int p = bxx * 256 + tid;
    int y = p >> 9, x = p & 511;
    const float* im = img + (size_t)bc * HW;
    float a = loadpix(im, y-1, x-1, IW), b2 = loadpix(im, y-1, x, IW), c2 = loadpix(im, y-1, x+1, IW);
    float d2 = loadpix(im, y, x-1, IW), e2 = loadpix(im, y, x+1, IW);
    float f2 = loadpix(im, y+1, x-1, IW), h2 = loadpix(im, y+1, x, IW), i9 = loadpix(im, y+1, x+1, IW);
    float g0 = -3.f*a + 3.f*c2 + 10.f*d2 + 10.f*e2 - 3.f*f2 + 3.f*i9;
    float g1 = -3.f*a + 10.f*b2 - 3.f*c2 + 3.f*f2 + 10.f*h2 + 3.f*i9;
    gmaps[((size_t)(bc*2+0))*HW + p] = g0;
    gmaps[((size_t)(bc*2+1))*HW + p] = g1;
    const float cs = 0.7071067811865476f;  // cos(-45); sin(-45) = -cs
    float xg = (float)(x + 105) - 512.5f;
    float yg = (float)(y + 105) - 512.5f;
    float t1 = cs*xg, t2 = cs*yg;
    float xi = (t1+t2) + 362.0f;
    float yi = (-t1+t2) + 362.0f;
    int xn = (int)rintf(xi);
    int yn = (int)rintf(yi);
    float r0 = 0.f, r1 = 0.f;
    if (xn >= 0 && xn < RN && yn >= 0 && yn < RN) {
        float ra = rtap(im, xn-1, yn-1), rb = rtap(im, xn, yn-1), rc = rtap(im, xn+1, yn-1);
        float rd = rtap(im, xn-1, yn),   re = rtap(im, xn+1, yn);
        float rf = rtap(im, xn-1, yn+1), rh = rtap(im, xn, yn+1), ri = rtap(im, xn+1, yn+1);
        r0 = -3.f*ra + 3.f*rc + 10.f*rd + 10.f*re - 3.f*rf + 3.f*ri;
        r1 = -3.f*ra + 10.f*rb - 3.f*rc + 3.f*rf + 10.f*rh + 3.f*ri;
    }
    gmaps[((size_t)(12 + bc*2+0))*HW + p] = r0;
    gmaps[((size_t)(12 + bc*2+1))*HW + p] = r1;
    __shared__ float slo[4][256], shi[4][256];
    slo[0][tid] = g0; shi[0][tid] = g0;
    slo[1][tid] = g1; shi[1][tid] = g1;
    slo[2][tid] = r0; shi[2][tid] = r0;
    slo[3][tid] = r1; shi[3][tid] = r1;
    __syncthreads();
    for (int off = 128; off > 0; off >>= 1) {
        if (tid < off) {
            #pragma unroll
            for (int k = 0; k < 4; ++k) {
                slo[k][tid] = fminf(slo[k][tid], slo[k][tid + off]);
                shi[k][tid] = fmaxf(shi[k][tid], shi[k][tid + off]);
            }
        }
        __syncthreads();
    }
    if (tid < 4) {
        int m = (tid < 2) ? (bc*2 + tid) : (12 + bc*2 + (tid - 2));
        pmin[m * NBLK + bxx] = slo[tid][0];
        pmax[m * NBLK + bxx] = shi[tid][0];
    }
}

// ---- color hist + (c==0) region sizes & bbox ----
// 64 splits/gy = 1152 blocks = 4.5 blocks/CU (32 splits was 2.25/CU — the
// lowest-occupancy latency-bound kernel in the pipeline).
__global__ __launch_bounds__(256) void k_regchist(
    const float* __restrict__ img, const int* __restrict__ lab,
    float* __restrict__ rs_out, int* __restrict__ bbmin, int* __restrict__ bbmax,
    float* __restrict__ ch_out)
{
    __shared__ unsigned cnt[NSEG * 25];
    __shared__ unsigned rcnt[NSEG];
    __shared__ int sxmin[NSEG], sxmax[NSEG], symin[NSEG], symax[NSEG];
    int gy = blockIdx.y;       // (b*3+g)*3 + c
    int c = gy % 3;
    int bg = gy / 3;
    int b = bg / 3;
    int tid = threadIdx.x;
    bool do_reg = (c == 0);
    for (int i = tid; i < NSEG * 25; i += 256) cnt[i] = 0;
    if (do_reg) {
        rcnt[tid] = 0; sxmin[tid] = INT_MAX; sxmax[tid] = INT_MIN;
        symin[tid] = INT_MAX; symax[tid] = INT_MIN;
    }
    __syncthreads();
    const float4* ip = (const float4*)(img + ((size_t)b * 3 + c) * HW);
    const int4* lp = (const int4*)(lab + (size_t)bg * HW);
    int stride = 256 * gridDim.x;
    for (int i = blockIdx.x * 256 + tid; i < HW / 4; i += stride) {
        float4 v4 = ip[i];
        int4 l4 = lp[i];
        int l0 = l4.x & 255, l1 = l4.y & 255, l2 = l4.z & 255, l3 = l4.w & 255;
        int b0 = (int)((float)l0 * 25.0f + v4.x * 24.0f);
        int b1 = (int)((float)l1 * 25.0f + v4.y * 24.0f);
        int b2 = (int)((float)l2 * 25.0f + v4.z * 24.0f);
        int b3 = (int)((float)l3 * 25.0f + v4.w * 24.0f);
        b0 = min(max(b0, 0), 6399); b1 = min(max(b1, 0), 6399);
        b2 = min(max(b2, 0), 6399); b3 = min(max(b3, 0), 6399);
        atomicAdd(&cnt[b0], 1u); atomicAdd(&cnt[b1], 1u);
        atomicAdd(&cnt[b2], 1u); atomicAdd(&cnt[b3], 1u);
        if (do_reg) {
            int p = i << 2;
            int y = p >> 9, x = p & 511;
            atomicAdd(&rcnt[l0], 1u); atomicAdd(&rcnt[l1], 1u);
            atomicAdd(&rcnt[l2], 1u); atomicAdd(&rcnt[l3], 1u);
            atomicMin(&sxmin[l0], x);     atomicMax(&sxmax[l0], x);
            atomicMin(&sxmin[l1], x + 1); atomicMax(&sxmax[l1], x + 1);
            atomicMin(&sxmin[l2], x + 2); atomicMax(&sxmax[l2], x + 2);
            atomicMin(&sxmin[l3], x + 3); atomicMax(&sxmax[l3], x + 3);
            atomicMin(&symin[l0], y); atomicMax(&symax[l0], y);
            atomicMin(&symin[l1], y); atomicMax(&symax[l1], y);
            atomicMin(&symin[l2], y); atomicMax(&symax[l2], y);
            atomicMin(&symin[l3], y); atomicMax(&symax[l3], y);
        }
    }
    __syncthreads();
    for (int i = tid; i < NSEG * 25; i += 256) {
        unsigned n = cnt[i];
        if (n) {
            int s = i / 25, cb = i - s * 25;
            atomicAdd(&ch_out[((size_t)(bg * NSEG + s) * 3 + c) * 25 + cb], (float)n);
        }
    }
    if (do_reg) {
        if (rcnt[tid]) atomicAdd(&rs_out[bg * NSEG + tid], (float)rcnt[tid]);
        if (sxmin[tid] != INT_MAX) {
            atomicMin(&bbmin[bg * NSEG + tid], sxmin[tid]);
            atomicMax(&bbmax[bg * NSEG + tid], sxmax[tid]);
            atomicMin(&bbmin[1536 + bg * NSEG + tid], symin[tid]);
            atomicMax(&bbmax[1536 + bg * NSEG + tid], symax[tid]);
        }
    }
}

// ---- texture histogram: ONE LDS atomic/pixel; mm reduced inline from partials ----
__global__ __launch_bounds__(256) void k_thist(
    const float* __restrict__ maps, const int* __restrict__ lab,
    const float* __restrict__ pmin, const float* __restrict__ pmax,
    unsigned* __restrict__ thp)
{
    __shared__ unsigned cnt[2 * 2560];  // [0,2560) pos-side data bins, [2560,5120) neg
    __shared__ float slo[256], shi[256];
    int gy = blockIdx.y;
    int gi = gy % 3;
    int r = gy / 3;
    int base = r & 1;
    int bd = r >> 1;
    int d = bd & 1;
    int bc = bd >> 1;
    int b = bc / 3;
    int m = base * 12 + bc * 2 + d;
    float mn, mx;
    mm_of_map(pmin, pmax, m, slo, shi, mn, mx);
    for (int i = threadIdx.x; i < 5120; i += 256) cnt[i] = 0;
    __syncthreads();
    float hminp = fmaxf(mn, 0.f), denp = fmaxf(mx, 0.f) - hminp;
    float hminn = fminf(mn, 0.f), denn = fminf(mx, 0.f) - hminn;
    const float4* src = (const float4*)(maps + (size_t)m * HW);
    const int4* lp = (const int4*)(lab + (size_t)(b * 3 + gi) * HW);
    int stride = 256 * gridDim.x;
    for (int i = blockIdx.x * 256 + threadIdx.x; i < HW / 4; i += stride) {
        float4 v4 = src[i];
        int4 l4 = lp[i];
#define TH1(V, L)                                                      \
        {                                                              \
            float v = (V);                                             \
            float la = (float)((L) & 255);                             \
            bool ge = (v >= 0.f);                                      \
            float hm = ge ? hminp : hminn;                             \
            float dn = ge ? denp : denn;                               \
            float t9 = ((v - hm) / dn) * 9.0f;                         \
            int bi = (int)(la * 10.0f + t9);                           \
            bi = min(max(bi, 0), 2559);                                \
            atomicAdd(&cnt[(ge ? 0 : 2560) + bi], 1u);                 \
        }
        TH1(v4.x, l4.x) TH1(v4.y, l4.y) TH1(v4.z, l4.z) TH1(v4.w, l4.w)
#undef TH1
    }
    __syncthreads();
    unsigned* dst = thp + ((size_t)gy * THP + blockIdx.x) * 5120;
    for (int i = threadIdx.x; i < 5120; i += 256) dst[i] = cnt[i];
}

// ---- fused: th partial-reduce + sign-completion + normalize (bx<72); ch + xywh (else) ----
__global__ __launch_bounds__(256) void k_thfinal(
    const unsigned* __restrict__ thp, const float* __restrict__ pmin,
    const float* __restrict__ pmax, const int* __restrict__ bbmin,
    const int* __restrict__ bbmax, float* __restrict__ out)
{
    int tid = threadIdx.x;
    int bx = blockIdx.x;
    if (bx < 72) {
        __shared__ unsigned hist[5120];
        __shared__ float slo[256], shi[256];
        int gy = bx;
        int gi = gy % 3; int r = gy / 3; int base = r & 1;
        int bd = r >> 1; int d = bd & 1; int bc = bd >> 1;
        int b = bc / 3, c = bc - b * 3;
        int m = base * 12 + bc * 2 + d;
        float mn, mx;
        mm_of_map(pmin, pmax, m, slo, shi, mn, mx);
        for (int i = tid; i < 5120; i += 256) {
            unsigned s = 0;
            for (int p = 0; p < THP; ++p) s += thp[((size_t)(gy * THP + p)) * 5120 + i];
            hist[i] = s;
        }
        __syncthreads();
        {
            int l = tid;   // one thread per label: sign-completion
            unsigned nge = 0;
            for (int tb = 0; tb < 10; ++tb) nge += hist[l * 10 + tb];   // v>=0 pixel count
            float rsf = out[(b * 3 + gi) * NSEG + l];
            unsigned rsu = (unsigned)rsf;
            unsigned nlt = (rsu >= nge) ? (rsu - nge) : 0u;              // v<0 pixel count
            float hminp = fmaxf(mn, 0.f), denp = fmaxf(mx, 0.f) - hminp;
            float hminn = fminf(mn, 0.f), denn = fminf(mx, 0.f) - hminn;
            float la = (float)l;
            float tp0 = ((0.0f - hminp) / denp) * 9.0f;   // pos bin of clipped (v<0) pixels
            float tn0 = ((0.0f - hminn) / denn) * 9.0f;   // neg bin of clipped (v>=0) pixels
            int bp = (int)(la * 10.0f + tp0); bp = min(max(bp, 0), 2559);
            int bn = (int)(la * 10.0f + tn0); bn = min(max(bn, 0), 2559);
            if (nlt) atomicAdd(&hist[bp], nlt);
            if (nge) atomicAdd(&hist[2560 + bn], nge);
        }
        __syncthreads();
        for (int i = tid; i < 5120; i += 256) {
            int pos = (i < 2560);
            int rr = pos ? i : i - 2560;
            int seg = rr / 10, tb = rr - seg * 10;
            int t = base * 4 + (pos ? 0 : 2) + d;
            float rsf = out[(b * 3 + gi) * NSEG + seg];
            out[TH_OFF + ((size_t)((b * 3 + gi) * NSEG + seg) * 3 + c) * 80 + t * 10 + tb] =
                (float)hist[i] / (24.0f * rsf);
        }
    } else {
        for (int seg = bx - 72; seg < 1536; seg += (gridDim.x - 72)) {
            float rsf = out[seg];
            float cd = 3.0f * rsf;
            float* ch = out + CH_OFF + (size_t)seg * 75;
            for (int i = tid; i < 75; i += 256) ch[i] = ch[i] / cd;
            if (tid == 0) {
                int xmin, xmax, ymin, ymax;
                if (rsf > 0.f) {
                    xmin = bbmin[seg]; ymin = bbmin[1536 + seg];
                    xmax = bbmax[seg]; ymax = bbmax[1536 + seg];
                } else {
                    xmin = IW; ymin = IW; xmax = 0; ymax = 0;
                }
                float* xy = out + XY_OFF + (size_t)seg * 4;
                xy[0] = (float)xmin; xy[1] = (float)ymin;
                xy[2] = (float)(xmax - xmin); xy[3] = (float)(ymax - ymin);
            }
        }
    }
}

extern "C" void kernel_launch(void* const* d_in, const int* in_sizes, int n_in,
                              void* d_out, int out_size, void* d_ws, size_t ws_size,
                              hipStream_t stream) {
    const float* img = (const float*)d_in[0];
    const int* lab = (const int*)d_in[1];
    float* out = (float*)d_out;

    float* gmaps = (float*)d_ws;                        // 24 maps * 262144 f32 (25.2 MB)
    float* pmin = gmaps + (size_t)24 * HW;              // 24*1024
    float* pmax = pmin + 24 * NBLK;
    int* bbmin = (int*)(pmax + 24 * NBLK);              // 3072: [xmin(1536), ymin(1536)]
    int* bbmax = bbmin + 3072;                          // 3072: [xmax(1536), ymax(1536)]
    unsigned* thp = (unsigned*)(bbmax + 3072);          // 72*THP*5120 u32 (~23.6 MB)

    hipLaunchKernelGGL(k_grad, dim3(NBLK, 6), dim3(256), 0, stream,
                       img, gmaps, pmin, pmax, out, bbmin, bbmax);
    hipLaunchKernelGGL(k_regchist, dim3(64, 18), dim3(256), 0, stream,
                       img, lab, out, bbmin, bbmax, out + CH_OFF);
    hipLaunchKernelGGL(k_thist, dim3(THP, 72), dim3(256), 0, stream, gmaps, lab, pmin, pmax, thp);
    hipLaunchKernelGGL(k_thfinal, dim3(72 + 256), dim3(256), 0, stream, thp, pmin, pmax, bbmin, bbmax, out);
}

// Round 15
// 156.524 us; speedup vs baseline: 1.2431x; 1.2431x over previous
//
#include <hip/hip_runtime.h>
#include <climits>

#define HW 262144          // 512*512
#define IW 512
#define RN 725             // virtual rotated canvas side
#define NSEG 256
#define CH_OFF 1536
#define TH_OFF 116736
#define XY_OFF 485376
#define NBLK 1024          // blocks per image plane in k_grad; minmax partial count
#define THP 16             // pixel splits in k_thist
#define CHP 32             // pixel splits in k_regchist

static __device__ __forceinline__ float loadpix(const float* p, int y, int x, int n) {
    return (y >= 0 && y < n && x >= 0 && x < n) ? p[y * n + x] : 0.0f;
}

// virtual rot-canvas sample: canvas coord (cx,cy) -> nearest img pixel (exact rot formula)
static __device__ __forceinline__ float rtap(const float* __restrict__ im, int cx, int cy) {
    if (cx < 0 || cx >= RN || cy < 0 || cy >= RN) return 0.f;
    const float cs = 0.7071067811865476f;
    float xg = (float)cx - 362.0f;
    float yg = (float)cy - 362.0f;
    float xi = cs * xg - cs * yg + 255.5f;
    float yi = cs * xg + cs * yg + 255.5f;
    int xn = (int)rintf(xi);
    int yn = (int)rintf(yi);
    if (xn < 0 || xn >= IW || yn < 0 || yn >= IW) return 0.f;
    return im[yn * IW + xn];
}

// block-level min/max of map m's NBLK partials; all threads get (mn,mx)
static __device__ __forceinline__ void mm_of_map(const float* __restrict__ pmin,
                                                 const float* __restrict__ pmax,
                                                 int m, float* slo, float* shi,
                                                 float& mn, float& mx) {
    int tid = threadIdx.x;
    float lo = 3.4e38f, hi = -3.4e38f;
    for (int i = tid; i < NBLK; i += 256) {
        lo = fminf(lo, pmin[m * NBLK + i]);
        hi = fmaxf(hi, pmax[m * NBLK + i]);
    }
    slo[tid] = lo; shi[tid] = hi;
    __syncthreads();
    for (int off = 128; off > 0; off >>= 1) {
        if (tid < off) {
            slo[tid] = fminf(slo[tid], slo[tid + off]);
            shi[tid] = fmaxf(shi[tid], shi[tid + off]);
        }
        __syncthreads();
    }
    mn = slo[0]; mx = shi[0];
    __syncthreads();
}

// ---- gradients (f32) + LDS-tree min/max partials + init chores ----
// LDS tree (not __shfl_xor butterfly: 48 ds_swizzles/thread cost ~11us, r10).
// No cross-block handoff (threadfence last-block cost ~150us, r11); stream-ordered
// kernel boundaries are the cheapest device-wide barrier on MI355X.
__global__ __launch_bounds__(256) void k_grad(
    const float* __restrict__ img, float* __restrict__ gmaps,
    float* __restrict__ pmin, float* __restrict__ pmax,
    float* __restrict__ out, int* __restrict__ bbmin, int* __restrict__ bbmax)
{
    int bxx = blockIdx.x;
    int bc = blockIdx.y;
    int tid = threadIdx.x;
    // init chores for later-launched consumers (stream order covers visibility)
    if (bc == 0 && bxx < 6) {                   // zero rs: 6*256 == 1536
        out[bxx * 256 + tid] = 0.0f;
    } else if (bc == 1 && bxx < 12) {           // bbox init: 12*256 == 2*3072
        int i = bxx * 256 + tid;
        bbmin[i] = INT_MAX;
        bbmax[i] = INT_MIN;
    }
    int p = bxx * 256 + tid;
    int y = p >> 9, x = p & 511;
    const float* im = img + (size_t)bc * HW;
    float a = loadpix(im, y-1, x-1, IW), b2 = loadpix(im, y-1, x, IW), c2 = loadpix(im, y-1, x+1, IW);
    float d2 = loadpix(im, y, x-1, IW), e2 = loadpix(im, y, x+1, IW);
    float f2 = loadpix(im, y+1, x-1, IW), h2 = loadpix(im, y+1, x, IW), i9 = loadpix(im, y+1, x+1, IW);
    float g0 = -3.f*a + 3.f*c2 + 10.f*d2 + 10.f*e2 - 3.f*f2 + 3.f*i9;
    float g1 = -3.f*a + 10.f*b2 - 3.f*c2 + 3.f*f2 + 10.f*h2 + 3.f*i9;
    gmaps[((size_t)(bc*2+0))*HW + p] = g0;
    gmaps[((size_t)(bc*2+1))*HW + p] = g1;
    const float cs = 0.7071067811865476f;  // cos(-45); sin(-45) = -cs
    float xg = (float)(x + 105) - 512.5f;
    float yg = (float)(y + 105) - 512.5f;
    float t1 = cs*xg, t2 = cs*yg;
    float xi = (t1+t2) + 362.0f;
    float yi = (-t1+t2) + 362.0f;
    int xn = (int)rintf(xi);
    int yn = (int)rintf(yi);
    float r0 = 0.f, r1 = 0.f;
    if (xn >= 0 && xn < RN && yn >= 0 && yn < RN) {
        float ra = rtap(im, xn-1, yn-1), rb = rtap(im, xn, yn-1), rc = rtap(im, xn+1, yn-1);
        float rd = rtap(im, xn-1, yn),   re = rtap(im, xn+1, yn);
        float rf = rtap(im, xn-1, yn+1), rh = rtap(im, xn, yn+1), ri = rtap(im, xn+1, yn+1);
        r0 = -3.f*ra + 3.f*rc + 10.f*rd + 10.f*re - 3.f*rf + 3.f*ri;
        r1 = -3.f*ra + 10.f*rb - 3.f*rc + 3.f*rf + 10.f*rh + 3.f*ri;
    }
    gmaps[((size_t)(12 + bc*2+0))*HW + p] = r0;
    gmaps[((size_t)(12 + bc*2+1))*HW + p] = r1;
    __shared__ float slo[4][256], shi[4][256];
    slo[0][tid] = g0; shi[0][tid] = g0;
    slo[1][tid] = g1; shi[1][tid] = g1;
    slo[2][tid] = r0; shi[2][tid] = r0;
    slo[3][tid] = r1; shi[3][tid] = r1;
    __syncthreads();
    for (int off = 128; off > 0; off >>= 1) {
        if (tid < off) {
            #pragma unroll
            for (int k = 0; k < 4; ++k) {
                slo[k][tid] = fminf(slo[k][tid], slo[k][tid + off]);
                shi[k][tid] = fmaxf(shi[k][tid], shi[k][tid + off]);
            }
        }
        __syncthreads();
    }
    if (tid < 4) {
        int m = (tid < 2) ? (bc*2 + tid) : (12 + bc*2 + (tid - 2));
        pmin[m * NBLK + bxx] = slo[tid][0];
        pmax[m * NBLK + bxx] = shi[tid][0];
    }
}

// ---- color hist (partial write, NO atomic flush) + (c==0) region sizes & bbox ----
// r14: atomic flush of 6400 bins/block was the cost center (3.7M+ global atomics,
// 37MB WRITE). Deterministic partials + reduce-in-thfinal is the thist-proven fix.
__global__ __launch_bounds__(256) void k_regchist(
    const float* __restrict__ img, const int* __restrict__ lab,
    float* __restrict__ rs_out, int* __restrict__ bbmin, int* __restrict__ bbmax,
    unsigned* __restrict__ chp)
{
    __shared__ unsigned cnt[NSEG * 25];
    __shared__ unsigned rcnt[NSEG];
    __shared__ int sxmin[NSEG], sxmax[NSEG], symin[NSEG], symax[NSEG];
    int gy = blockIdx.y;       // (b*3+g)*3 + c
    int c = gy % 3;
    int bg = gy / 3;
    int b = bg / 3;
    int tid = threadIdx.x;
    bool do_reg = (c == 0);
    for (int i = tid; i < NSEG * 25; i += 256) cnt[i] = 0;
    if (do_reg) {
        rcnt[tid] = 0; sxmin[tid] = INT_MAX; sxmax[tid] = INT_MIN;
        symin[tid] = INT_MAX; symax[tid] = INT_MIN;
    }
    __syncthreads();
    const float4* ip = (const float4*)(img + ((size_t)b * 3 + c) * HW);
    const int4* lp = (const int4*)(lab + (size_t)bg * HW);
    int stride = 256 * gridDim.x;
    for (int i = blockIdx.x * 256 + tid; i < HW / 4; i += stride) {
        float4 v4 = ip[i];
        int4 l4 = lp[i];
        int l0 = l4.x & 255, l1 = l4.y & 255, l2 = l4.z & 255, l3 = l4.w & 255;
        int b0 = (int)((float)l0 * 25.0f + v4.x * 24.0f);
        int b1 = (int)((float)l1 * 25.0f + v4.y * 24.0f);
        int b2 = (int)((float)l2 * 25.0f + v4.z * 24.0f);
        int b3 = (int)((float)l3 * 25.0f + v4.w * 24.0f);
        b0 = min(max(b0, 0), 6399); b1 = min(max(b1, 0), 6399);
        b2 = min(max(b2, 0), 6399); b3 = min(max(b3, 0), 6399);
        atomicAdd(&cnt[b0], 1u); atomicAdd(&cnt[b1], 1u);
        atomicAdd(&cnt[b2], 1u); atomicAdd(&cnt[b3], 1u);
        if (do_reg) {
            int p = i << 2;
            int y = p >> 9, x = p & 511;
            atomicAdd(&rcnt[l0], 1u); atomicAdd(&rcnt[l1], 1u);
            atomicAdd(&rcnt[l2], 1u); atomicAdd(&rcnt[l3], 1u);
            atomicMin(&sxmin[l0], x);     atomicMax(&sxmax[l0], x);
            atomicMin(&sxmin[l1], x + 1); atomicMax(&sxmax[l1], x + 1);
            atomicMin(&sxmin[l2], x + 2); atomicMax(&sxmax[l2], x + 2);
            atomicMin(&sxmin[l3], x + 3); atomicMax(&sxmax[l3], x + 3);
            atomicMin(&symin[l0], y); atomicMax(&symax[l0], y);
            atomicMin(&symin[l1], y); atomicMax(&symax[l1], y);
            atomicMin(&symin[l2], y); atomicMax(&symax[l2], y);
            atomicMin(&symin[l3], y); atomicMax(&symax[l3], y);
        }
    }
    __syncthreads();
    // coalesced partial store: zero atomics
    unsigned* dst = chp + ((size_t)gy * CHP + blockIdx.x) * 6400;
    for (int i = tid; i < NSEG * 25; i += 256) dst[i] = cnt[i];
    if (do_reg) {
        if (rcnt[tid]) atomicAdd(&rs_out[bg * NSEG + tid], (float)rcnt[tid]);
        if (sxmin[tid] != INT_MAX) {
            atomicMin(&bbmin[bg * NSEG + tid], sxmin[tid]);
            atomicMax(&bbmax[bg * NSEG + tid], sxmax[tid]);
            atomicMin(&bbmin[1536 + bg * NSEG + tid], symin[tid]);
            atomicMax(&bbmax[1536 + bg * NSEG + tid], symax[tid]);
        }
    }
}

// ---- texture histogram: ONE LDS atomic/pixel; mm reduced inline from partials ----
__global__ __launch_bounds__(256) void k_thist(
    const float* __restrict__ maps, const int* __restrict__ lab,
    const float* __restrict__ pmin, const float* __restrict__ pmax,
    unsigned* __restrict__ thp)
{
    __shared__ unsigned cnt[2 * 2560];  // [0,2560) pos-side data bins, [2560,5120) neg
    __shared__ float slo[256], shi[256];
    int gy = blockIdx.y;
    int gi = gy % 3;
    int r = gy / 3;
    int base = r & 1;
    int bd = r >> 1;
    int d = bd & 1;
    int bc = bd >> 1;
    int b = bc / 3;
    int m = base * 12 + bc * 2 + d;
    float mn, mx;
    mm_of_map(pmin, pmax, m, slo, shi, mn, mx);
    for (int i = threadIdx.x; i < 5120; i += 256) cnt[i] = 0;
    __syncthreads();
    float hminp = fmaxf(mn, 0.f), denp = fmaxf(mx, 0.f) - hminp;
    float hminn = fminf(mn, 0.f), denn = fminf(mx, 0.f) - hminn;
    const float4* src = (const float4*)(maps + (size_t)m * HW);
    const int4* lp = (const int4*)(lab + (size_t)(b * 3 + gi) * HW);
    int stride = 256 * gridDim.x;
    for (int i = blockIdx.x * 256 + threadIdx.x; i < HW / 4; i += stride) {
        float4 v4 = src[i];
        int4 l4 = lp[i];
#define TH1(V, L)                                                      \
        {                                                              \
            float v = (V);                                             \
            float la = (float)((L) & 255);                             \
            bool ge = (v >= 0.f);                                      \
            float hm = ge ? hminp : hminn;                             \
            float dn = ge ? denp : denn;                               \
            float t9 = ((v - hm) / dn) * 9.0f;                         \
            int bi = (int)(la * 10.0f + t9);                           \
            bi = min(max(bi, 0), 2559);                                \
            atomicAdd(&cnt[(ge ? 0 : 2560) + bi], 1u);                 \
        }
        TH1(v4.x, l4.x) TH1(v4.y, l4.y) TH1(v4.z, l4.z) TH1(v4.w, l4.w)
#undef TH1
    }
    __syncthreads();
    unsigned* dst = thp + ((size_t)gy * THP + blockIdx.x) * 5120;
    for (int i = threadIdx.x; i < 5120; i += 256) dst[i] = cnt[i];
}

// ---- fused: th partial-reduce + sign-completion + normalize (bx<72);
//      ch partial-reduce + normalize + xywh (else) ----
__global__ __launch_bounds__(256) void k_thfinal(
    const unsigned* __restrict__ thp, const unsigned* __restrict__ chp,
    const float* __restrict__ pmin, const float* __restrict__ pmax,
    const int* __restrict__ bbmin, const int* __restrict__ bbmax,
    float* __restrict__ out)
{
    int tid = threadIdx.x;
    int bx = blockIdx.x;
    if (bx < 72) {
        __shared__ unsigned hist[5120];
        __shared__ float slo[256], shi[256];
        int gy = bx;
        int gi = gy % 3; int r = gy / 3; int base = r & 1;
        int bd = r >> 1; int d = bd & 1; int bc = bd >> 1;
        int b = bc / 3, c = bc - b * 3;
        int m = base * 12 + bc * 2 + d;
        float mn, mx;
        mm_of_map(pmin, pmax, m, slo, shi, mn, mx);
        for (int i = tid; i < 5120; i += 256) {
            unsigned s = 0;
            for (int p = 0; p < THP; ++p) s += thp[((size_t)(gy * THP + p)) * 5120 + i];
            hist[i] = s;
        }
        __syncthreads();
        {
            int l = tid;   // one thread per label: sign-completion
            unsigned nge = 0;
            for (int tb = 0; tb < 10; ++tb) nge += hist[l * 10 + tb];   // v>=0 pixel count
            float rsf = out[(b * 3 + gi) * NSEG + l];
            unsigned rsu = (unsigned)rsf;
            unsigned nlt = (rsu >= nge) ? (rsu - nge) : 0u;              // v<0 pixel count
            float hminp = fmaxf(mn, 0.f), denp = fmaxf(mx, 0.f) - hminp;
            float hminn = fminf(mn, 0.f), denn = fminf(mx, 0.f) - hminn;
            float la = (float)l;
            float tp0 = ((0.0f - hminp) / denp) * 9.0f;   // pos bin of clipped (v<0) pixels
            float tn0 = ((0.0f - hminn) / denn) * 9.0f;   // neg bin of clipped (v>=0) pixels
            int bp = (int)(la * 10.0f + tp0); bp = min(max(bp, 0), 2559);
            int bn = (int)(la * 10.0f + tn0); bn = min(max(bn, 0), 2559);
            if (nlt) atomicAdd(&hist[bp], nlt);
            if (nge) atomicAdd(&hist[2560 + bn], nge);
        }
        __syncthreads();
        for (int i = tid; i < 5120; i += 256) {
            int pos = (i < 2560);
            int rr = pos ? i : i - 2560;
            int seg = rr / 10, tb = rr - seg * 10;
            int t = base * 4 + (pos ? 0 : 2) + d;
            float rsf = out[(b * 3 + gi) * NSEG + seg];
            out[TH_OFF + ((size_t)((b * 3 + gi) * NSEG + seg) * 3 + c) * 80 + t * 10 + tb] =
                (float)hist[i] / (24.0f * rsf);
        }
    } else {
        for (int seg = bx - 72; seg < 1536; seg += (gridDim.x - 72)) {
            int bg = seg >> 8;        // seg = bg*256 + s
            int s = seg & 255;
            float rsf = out[seg];
            float cd = 3.0f * rsf;
            float* ch = out + CH_OFF + (size_t)seg * 75;
            // reduce CHP partials for this seg's 75 (c,cb) bins; coalesced 25-bursts
            for (int i = tid; i < 75; i += 256) {
                int c = i / 25, cb = i - c * 25;
                unsigned sum = 0;
                const unsigned* src = chp + ((size_t)(bg * 3 + c) * CHP) * 6400 + s * 25 + cb;
                #pragma unroll 4
                for (int p = 0; p < CHP; ++p) sum += src[(size_t)p * 6400];
                ch[i] = (float)sum / cd;
            }
            if (tid == 0) {
                int xmin, xmax, ymin, ymax;
                if (rsf > 0.f) {
                    xmin = bbmin[seg]; ymin = bbmin[1536 + seg];
                    xmax = bbmax[seg]; ymax = bbmax[1536 + seg];
                } else {
                    xmin = IW; ymin = IW; xmax = 0; ymax = 0;
                }
                float* xy = out + XY_OFF + (size_t)seg * 4;
                xy[0] = (float)xmin; xy[1] = (float)ymin;
                xy[2] = (float)(xmax - xmin); xy[3] = (float)(ymax - ymin);
            }
        }
    }
}

extern "C" void kernel_launch(void* const* d_in, const int* in_sizes, int n_in,
                              void* d_out, int out_size, void* d_ws, size_t ws_size,
                              hipStream_t stream) {
    const float* img = (const float*)d_in[0];
    const int* lab = (const int*)d_in[1];
    float* out = (float*)d_out;

    float* gmaps = (float*)d_ws;                        // 24 maps * 262144 f32 (25.2 MB)
    float* pmin = gmaps + (size_t)24 * HW;              // 24*1024
    float* pmax = pmin + 24 * NBLK;
    int* bbmin = (int*)(pmax + 24 * NBLK);              // 3072: [xmin(1536), ymin(1536)]
    int* bbmax = bbmin + 3072;                          // 3072: [xmax(1536), ymax(1536)]
    unsigned* thp = (unsigned*)(bbmax + 3072);          // 72*THP*5120 u32 (~23.6 MB)
    unsigned* chp = thp + (size_t)72 * THP * 5120;      // 18*CHP*6400 u32 (~14.7 MB)

    hipLaunchKernelGGL(k_grad, dim3(NBLK, 6), dim3(256), 0, stream,
                       img, gmaps, pmin, pmax, out, bbmin, bbmax);
    hipLaunchKernelGGL(k_regchist, dim3(CHP, 18), dim3(256), 0, stream,
                       img, lab, out, bbmin, bbmax, chp);
    hipLaunchKernelGGL(k_thist, dim3(THP, 72), dim3(256), 0, stream, gmaps, lab, pmin, pmax, thp);
    hipLaunchKernelGGL(k_thfinal, dim3(72 + 256), dim3(256), 0, stream, thp, chp, pmin, pmax, bbmin, bbmax, out);
}